// Round 1
// baseline (147.207 us; speedup 1.0000x reference)
//
#include <hip/hip_runtime.h>
#include <hip/hip_bf16.h>
#include <stdint.h>

#define N_RES 256
#define CMDIM 256

typedef __attribute__((ext_vector_type(8))) short bf16x8;
typedef __attribute__((ext_vector_type(4))) float f32x4;
typedef __attribute__((ext_vector_type(2))) unsigned int u32x2;

__device__ __forceinline__ unsigned short f32_to_bf16(float f) {
    union { float f; unsigned int u; } v; v.f = f;
    unsigned int u = v.u;
    return (unsigned short)((u + 0x7FFFu + ((u >> 16) & 1u)) >> 16);
}

// Fragment-linear layouts (all bf16):
//   A2f/B2f: element(row, s)  -> ((row>>4)*4  + (s>>5))*512 + ((s>>3)&3)*128 + (row&15)*8 + (s&7)
//   Wbf:     element(ch, cm)  -> ((ch>>4)*8  + (cm>>5))*512 + ((cm>>3)&3)*128 + (ch&15)*8 + (cm&7)
//   wof:     element(zo, k)   -> ((zo>>4)*32 + (k>>5))*512 + ((k>>3)&3)*128 + (zo&15)*8 + (k&7)
// A wave reading (blk, ks) does one coalesced 1 KB load at base + lane*16B.

// ---------------- K0: convert + repack weights ----------------
__global__ __launch_bounds__(256) void k_prep(
    const float* __restrict__ w1, const float* __restrict__ w2,
    const float* __restrict__ wo,
    unsigned short* __restrict__ Wbf, unsigned short* __restrict__ wof)
{
    int t = blockIdx.x * 256 + threadIdx.x;
    if (t < 16384) {
        int ch = t >> 8, cm = t & 255;
        float v = (ch < 32) ? w1[ch * 256 + cm] : w2[(ch - 32) * 256 + cm];
        int addr = ((ch >> 4) * 8 + (cm >> 5)) * 512 + ((cm >> 3) & 3) * 128 + (ch & 15) * 8 + (cm & 7);
        Wbf[addr] = f32_to_bf16(v);
    }
    if (t < 131072) {
        int zo = t >> 10, k = t & 1023;
        int addr = ((zo >> 4) * 32 + (k >> 5)) * 512 + ((k >> 3) & 3) * 128 + (zo & 15) * 8 + (k & 7);
        wof[addr] = f32_to_bf16(wo[t]);
    }
}

// ---------------- K1: LayerNorm + dual projection ----------------
// 1024 WGs: b = i*4 + sblk. LN 32 rows, MFMA D[64ch][32s] = W*mn^T,
// epilogue staged through LDS -> coalesced dwordx4 global stores.
__global__ __launch_bounds__(256) void k_ln_proj(
    const float* __restrict__ m, const float* __restrict__ lnw, const float* __restrict__ lnb,
    const float* __restrict__ b1, const float* __restrict__ b2,
    const unsigned short* __restrict__ Wbf,
    unsigned short* __restrict__ A2f, unsigned short* __restrict__ B2f)
{
    __shared__ unsigned short mn[32 * 256];   // 16 KB
    __shared__ unsigned short stg[2048];      // 4 KB epilogue staging
    int b = blockIdx.x;
    int i = b >> 2, sblk = b & 3;
    int tid = threadIdx.x;
    int wv = tid >> 6, lane = tid & 63;
    int quad = lane >> 4, l15 = lane & 15;

    f32x4 lw = *(const f32x4*)(lnw + lane * 4);
    f32x4 lb = *(const f32x4*)(lnb + lane * 4);

    #pragma unroll
    for (int r = 0; r < 8; ++r) {
        int sl = wv * 8 + r;
        int s = sblk * 32 + sl;
        const float* row = m + ((size_t)s * N_RES + i) * CMDIM;
        f32x4 x = *(const f32x4*)(row + lane * 4);
        float s1 = x[0] + x[1] + x[2] + x[3];
        float s2 = x[0]*x[0] + x[1]*x[1] + x[2]*x[2] + x[3]*x[3];
        #pragma unroll
        for (int off = 32; off; off >>= 1) {
            s1 += __shfl_xor(s1, off);
            s2 += __shfl_xor(s2, off);
        }
        float mu = s1 * (1.0f / 256.0f);
        float var = s2 * (1.0f / 256.0f) - mu * mu;
        float rstd = rsqrtf(var + 1e-5f);
        float n0 = (x[0] - mu) * rstd * lw[0] + lb[0];
        float n1 = (x[1] - mu) * rstd * lw[1] + lb[1];
        float n2 = (x[2] - mu) * rstd * lw[2] + lb[2];
        float n3 = (x[3] - mu) * rstd * lw[3] + lb[3];
        unsigned int p0 = (unsigned)f32_to_bf16(n0) | ((unsigned)f32_to_bf16(n1) << 16);
        unsigned int p1 = (unsigned)f32_to_bf16(n2) | ((unsigned)f32_to_bf16(n3) << 16);
        int chunk = lane >> 1;
        int pos = (chunk & 16) | ((chunk ^ sl) & 15);
        unsigned int* dst = (unsigned int*)((char*)mn + sl * 512 + pos * 16 + (lane & 1) * 8);
        dst[0] = p0; dst[1] = p1;
    }
    __syncthreads();

    bf16x8 af[8];
    #pragma unroll
    for (int ks = 0; ks < 8; ++ks)
        af[ks] = *(const bf16x8*)(Wbf + (wv * 8 + ks) * 512 + lane * 8);

    f32x4 acc[2];
    acc[0] = (f32x4){0.f, 0.f, 0.f, 0.f};
    acc[1] = (f32x4){0.f, 0.f, 0.f, 0.f};
    #pragma unroll
    for (int ks = 0; ks < 8; ++ks) {
        #pragma unroll
        for (int nb = 0; nb < 2; ++nb) {
            int sl = nb * 16 + l15;
            int chunk = ks * 4 + quad;
            int pos = (chunk & 16) | ((chunk ^ sl) & 15);
            bf16x8 bf = *(const bf16x8*)((char*)mn + sl * 512 + pos * 16);
            acc[nb] = __builtin_amdgcn_mfma_f32_16x16x32_bf16(af[ks], bf, acc[nb], 0, 0, 0);
        }
    }

    // Epilogue: quantize into stg in store-linear (frag-linear) order.
    // stg offset = (wv>>1)*1024 + (wv&1)*512 + ((sl>>3)&3)*128 + (quad*4+reg)*8 + (sl&7)
    const float* bsrc = (wv < 2) ? b1 : b2;
    f32x4 bias = *(const f32x4*)(bsrc + (wv & 1) * 16 + quad * 4);
    unsigned short* sbase = stg + (wv >> 1) * 1024 + (wv & 1) * 512 + quad * 32;
    #pragma unroll
    for (int nb = 0; nb < 2; ++nb) {
        int sl = nb * 16 + l15;
        int soff = ((sl >> 3) & 3) * 128 + (sl & 7);
        #pragma unroll
        for (int reg = 0; reg < 4; ++reg)
            sbase[soff + reg * 8] = f32_to_bf16(acc[nb][reg] + bias[reg]);
    }
    __syncthreads();

    // Coalesced write-out: thread t -> 16B at stg[t*8], global chunk (part,blk).
    int part = tid >> 7, blk = (tid >> 6) & 1, l = tid & 63;
    unsigned short* gdst = (part ? B2f : A2f) + ((i * 2 + blk) * 4 + sblk) * 512 + l * 8;
    *(bf16x8*)gdst = *(const bf16x8*)(stg + tid * 8);
}

// ---------------- K2: fused GEMM1+GEMM2, 64-pair tiles ----------------
// Grid 32x32: bx -> 8 i's, by -> 8 j's. 512 threads = 8 waves, 128 KB LDS.
// o LDS layout: byte addr = chunk*1024 + (pair ^ (chunk&63))*16 + (e&7)*2,
// chunk = e>>3 in [0,128), e = c*32+d, pair = il*8+jl in [0,64).
__global__ __launch_bounds__(512) void k_fused(
    const unsigned short* __restrict__ A2f, const unsigned short* __restrict__ B2f,
    const unsigned short* __restrict__ wof, const float* __restrict__ bo,
    float* __restrict__ out)
{
    __shared__ char olds[131072];
    int bx = blockIdx.x;               // 8 i's
    int by = blockIdx.y;               // 8 j's
    int tid = threadIdx.x, wv = tid >> 6, lane = tid & 63;
    int quad = lane >> 4, l15 = lane & 15;
    int wm = wv & 1, wn = wv >> 2 == 0 ? (wv >> 1) : (wv >> 1); // wn in [0,4)
    wn = wv >> 1;

    // ---- Stage A: o[64 pairs][1024] = (8j x 32d) x (8i x 32c), K = 128 s ----
    // Wave tile: rows (j,d) 128 (wm), cols (i,c) 64 (wn). acc[8][4] frags.
    const unsigned short* Abase = A2f + (size_t)((bx * 16 + wn * 4) * 4) * 512 + lane * 8;
    const unsigned short* Bbase = B2f + (size_t)((by * 16 + wm * 8) * 4) * 512 + lane * 8;

    f32x4 acc[8][4];
    #pragma unroll
    for (int a = 0; a < 8; ++a)
        #pragma unroll
        for (int b = 0; b < 4; ++b) acc[a][b] = (f32x4){0.f, 0.f, 0.f, 0.f};

    bf16x8 amC[8], amN[8], bnC[4], bnN[4];
    #pragma unroll
    for (int mb = 0; mb < 8; ++mb)
        amC[mb] = *(const bf16x8*)(Bbase + (size_t)(mb * 4) * 512);
    #pragma unroll
    for (int nb = 0; nb < 4; ++nb)
        bnC[nb] = *(const bf16x8*)(Abase + (size_t)(nb * 4) * 512);

    #pragma unroll
    for (int ks = 0; ks < 4; ++ks) {
        if (ks < 3) {
            #pragma unroll
            for (int mb = 0; mb < 8; ++mb)
                amN[mb] = *(const bf16x8*)(Bbase + (size_t)(mb * 4 + ks + 1) * 512);
            #pragma unroll
            for (int nb = 0; nb < 4; ++nb)
                bnN[nb] = *(const bf16x8*)(Abase + (size_t)(nb * 4 + ks + 1) * 512);
        }
        #pragma unroll
        for (int mb = 0; mb < 8; ++mb)
            #pragma unroll
            for (int nb = 0; nb < 4; ++nb)
                acc[mb][nb] = __builtin_amdgcn_mfma_f32_16x16x32_bf16(amC[mb], bnC[nb], acc[mb][nb], 0, 0, 0);
        #pragma unroll
        for (int mb = 0; mb < 8; ++mb) amC[mb] = amN[mb];
        #pragma unroll
        for (int nb = 0; nb < 4; ++nb) bnC[nb] = bnN[nb];
    }

    // write o tile: row m_=(jl,d) (A-side=B2f), col n_=(il,c) (B-side=A2f)
    #pragma unroll
    for (int mb = 0; mb < 8; ++mb) {
        int d0 = (mb & 1) * 16 + quad * 4;      // m_ & 31
        int jl = wm * 4 + (mb >> 1);
        #pragma unroll
        for (int nb = 0; nb < 4; ++nb) {
            int c = (nb & 1) * 16 + l15;        // n_ & 31
            int il = wn * 2 + (nb >> 1);
            int pair = il * 8 + jl;
            int e0 = c * 32 + d0;
            int chunk = e0 >> 3;
            int phys = pair ^ (chunk & 63);
            f32x4 a4 = acc[mb][nb];
            unsigned int p0 = (unsigned)f32_to_bf16(a4[0]) | ((unsigned)f32_to_bf16(a4[1]) << 16);
            unsigned int p1 = (unsigned)f32_to_bf16(a4[2]) | ((unsigned)f32_to_bf16(a4[3]) << 16);
            u32x2 pv = {p0, p1};
            *(u32x2*)(olds + chunk * 1024 + phys * 16 + (quad & 1) * 8) = pv;
        }
    }

    // ---- Stage B: D[zo 32][pair 32] per wave, K=1024, 4-deep ring ----
    // Wave tile: zg = wv>>1 (4 zo-groups of 32), pg = wv&1 (2 pair-groups of 32).
    int zg = wv >> 1, pg = wv & 1;
    const unsigned short* wbase = wof + (size_t)(zg * 64) * 512 + lane * 8;

    bf16x8 af2[4][2], bfr[4][2];
    // wof prologue loads issued BEFORE the barrier (no LDS dependency) to
    // hide their L2 latency under the sync drain.
    #pragma unroll
    for (int p = 0; p < 3; ++p)
        #pragma unroll
        for (int zb = 0; zb < 2; ++zb)
            af2[p][zb] = *(const bf16x8*)(wbase + (size_t)(zb * 32 + p) * 512);

    __syncthreads();

    #pragma unroll
    for (int p = 0; p < 3; ++p)
        #pragma unroll
        for (int pb = 0; pb < 2; ++pb) {
            int pair = pg * 32 + pb * 16 + l15;
            int chunk = p * 4 + quad;
            int phys = pair ^ (chunk & 63);
            bfr[p][pb] = *(const bf16x8*)(olds + chunk * 1024 + phys * 16);
        }

    f32x4 acc2[2][2];
    #pragma unroll
    for (int a = 0; a < 2; ++a)
        #pragma unroll
        for (int b = 0; b < 2; ++b) acc2[a][b] = (f32x4){0.f, 0.f, 0.f, 0.f};

    #pragma unroll
    for (int kt = 0; kt < 32; ++kt) {
        int slot = kt & 3;
        if (kt + 3 < 32) {
            int pf = kt + 3, ps = pf & 3;
            #pragma unroll
            for (int zb = 0; zb < 2; ++zb)
                af2[ps][zb] = *(const bf16x8*)(wbase + (size_t)(zb * 32 + pf) * 512);
            #pragma unroll
            for (int pb = 0; pb < 2; ++pb) {
                int pair = pg * 32 + pb * 16 + l15;
                int chunk = pf * 4 + quad;
                int phys = pair ^ (chunk & 63);
                bfr[ps][pb] = *(const bf16x8*)(olds + chunk * 1024 + phys * 16);
            }
        }
        #pragma unroll
        for (int zb = 0; zb < 2; ++zb)
            #pragma unroll
            for (int pb = 0; pb < 2; ++pb)
                acc2[zb][pb] = __builtin_amdgcn_mfma_f32_16x16x32_bf16(af2[slot][zb], bfr[slot][pb], acc2[zb][pb], 0, 0, 0);
    }

    // epilogue: z = (acc + bo) / n_seq
    #pragma unroll
    for (int zb = 0; zb < 2; ++zb) {
        int zo = zg * 32 + zb * 16 + quad * 4;
        f32x4 b4 = *(const f32x4*)(bo + zo);
        #pragma unroll
        for (int pb = 0; pb < 2; ++pb) {
            int pair = pg * 32 + pb * 16 + l15;
            int i = bx * 8 + (pair >> 3);
            int j = by * 8 + (pair & 7);
            f32x4 v;
            #pragma unroll
            for (int reg = 0; reg < 4; ++reg)
                v[reg] = (acc2[zb][pb][reg] + b4[reg]) * (1.0f / 128.0f);
            *(f32x4*)(out + ((size_t)(i * 256 + j)) * 128 + zo) = v;
        }
    }
}

extern "C" void kernel_launch(void* const* d_in, const int* in_sizes, int n_in,
                              void* d_out, int out_size, void* d_ws, size_t ws_size,
                              hipStream_t stream) {
    const float* m   = (const float*)d_in[0];
    const float* lnw = (const float*)d_in[1];
    const float* lnb = (const float*)d_in[2];
    const float* w1  = (const float*)d_in[3];
    const float* b1  = (const float*)d_in[4];
    const float* w2  = (const float*)d_in[5];
    const float* b2  = (const float*)d_in[6];
    const float* wo  = (const float*)d_in[7];
    const float* bo  = (const float*)d_in[8];
    float* out = (float*)d_out;
    char* ws = (char*)d_ws;

    unsigned short* Wbf = (unsigned short*)(ws);                            // 32 KB
    unsigned short* wof = (unsigned short*)(ws + 32768);                    // 256 KB
    unsigned short* A2f = (unsigned short*)(ws + 32768 + 262144);           // 2 MB
    unsigned short* B2f = (unsigned short*)(ws + 32768 + 262144 + 2097152); // 2 MB

    hipLaunchKernelGGL(k_prep, dim3(512), dim3(256), 0, stream, w1, w2, wo, Wbf, wof);
    hipLaunchKernelGGL(k_ln_proj, dim3(1024), dim3(256), 0, stream,
                       m, lnw, lnb, b1, b2, Wbf, A2f, B2f);
    hipLaunchKernelGGL(k_fused, dim3(32, 32), dim3(512), 0, stream,
                       A2f, B2f, wof, bo, out);
}

// Round 2
// 140.185 us; speedup vs baseline: 1.0501x; 1.0501x over previous
//
#include <hip/hip_runtime.h>
#include <hip/hip_bf16.h>
#include <stdint.h>

#define N_RES 256
#define CMDIM 256

typedef __attribute__((ext_vector_type(8))) short bf16x8;
typedef __attribute__((ext_vector_type(4))) float f32x4;
typedef __attribute__((ext_vector_type(2))) unsigned int u32x2;

__device__ __forceinline__ unsigned short f32_to_bf16(float f) {
    union { float f; unsigned int u; } v; v.f = f;
    unsigned int u = v.u;
    return (unsigned short)((u + 0x7FFFu + ((u >> 16) & 1u)) >> 16);
}

// Bank-spreading chunk swizzle: put chunk bits 2-5 (the write-side lane
// variation, i.e. column l15) into phys bits 0-3 (the bank field), and
// chunk bits 0-1 into phys bits 4-5 (slot-group only).
__device__ __forceinline__ int swz6(int x) {
    return ((x >> 2) & 7) | (((x >> 5) & 1) << 3) | ((x & 3) << 4);
}

// Fragment-linear layouts (all bf16):
//   A2f/B2f: element(row, s)  -> ((row>>4)*4  + (s>>5))*512 + ((s>>3)&3)*128 + (row&15)*8 + (s&7)
//   Wbf:     element(ch, cm)  -> ((ch>>4)*8  + (cm>>5))*512 + ((cm>>3)&3)*128 + (ch&15)*8 + (cm&7)
//   wof:     element(zo, k)   -> ((zo>>4)*32 + (k>>5))*512 + ((k>>3)&3)*128 + (zo&15)*8 + (k&7)
// A wave reading (blk, ks) does one coalesced 1 KB load at base + lane*16B.

// ---------------- K0: convert + repack weights ----------------
__global__ __launch_bounds__(256) void k_prep(
    const float* __restrict__ w1, const float* __restrict__ w2,
    const float* __restrict__ wo,
    unsigned short* __restrict__ Wbf, unsigned short* __restrict__ wof)
{
    int t = blockIdx.x * 256 + threadIdx.x;
    if (t < 16384) {
        int ch = t >> 8, cm = t & 255;
        float v = (ch < 32) ? w1[ch * 256 + cm] : w2[(ch - 32) * 256 + cm];
        int addr = ((ch >> 4) * 8 + (cm >> 5)) * 512 + ((cm >> 3) & 3) * 128 + (ch & 15) * 8 + (cm & 7);
        Wbf[addr] = f32_to_bf16(v);
    }
    if (t < 131072) {
        int zo = t >> 10, k = t & 1023;
        int addr = ((zo >> 4) * 32 + (k >> 5)) * 512 + ((k >> 3) & 3) * 128 + (zo & 15) * 8 + (k & 7);
        wof[addr] = f32_to_bf16(wo[t]);
    }
}

// ---------------- K1: LayerNorm + dual projection ----------------
__global__ __launch_bounds__(256) void k_ln_proj(
    const float* __restrict__ m, const float* __restrict__ lnw, const float* __restrict__ lnb,
    const float* __restrict__ b1, const float* __restrict__ b2,
    const unsigned short* __restrict__ Wbf,
    unsigned short* __restrict__ A2f, unsigned short* __restrict__ B2f)
{
    __shared__ unsigned short mn[32 * 256];   // 16 KB
    __shared__ unsigned short stg[2048];      // 4 KB epilogue staging
    int b = blockIdx.x;
    int i = b >> 2, sblk = b & 3;
    int tid = threadIdx.x;
    int wv = tid >> 6, lane = tid & 63;
    int quad = lane >> 4, l15 = lane & 15;

    f32x4 lw = *(const f32x4*)(lnw + lane * 4);
    f32x4 lb = *(const f32x4*)(lnb + lane * 4);

    #pragma unroll
    for (int r = 0; r < 8; ++r) {
        int sl = wv * 8 + r;
        int s = sblk * 32 + sl;
        const float* row = m + ((size_t)s * N_RES + i) * CMDIM;
        f32x4 x = *(const f32x4*)(row + lane * 4);
        float s1 = x[0] + x[1] + x[2] + x[3];
        float s2 = x[0]*x[0] + x[1]*x[1] + x[2]*x[2] + x[3]*x[3];
        #pragma unroll
        for (int off = 32; off; off >>= 1) {
            s1 += __shfl_xor(s1, off);
            s2 += __shfl_xor(s2, off);
        }
        float mu = s1 * (1.0f / 256.0f);
        float var = s2 * (1.0f / 256.0f) - mu * mu;
        float rstd = rsqrtf(var + 1e-5f);
        float n0 = (x[0] - mu) * rstd * lw[0] + lb[0];
        float n1 = (x[1] - mu) * rstd * lw[1] + lb[1];
        float n2 = (x[2] - mu) * rstd * lw[2] + lb[2];
        float n3 = (x[3] - mu) * rstd * lw[3] + lb[3];
        unsigned int p0 = (unsigned)f32_to_bf16(n0) | ((unsigned)f32_to_bf16(n1) << 16);
        unsigned int p1 = (unsigned)f32_to_bf16(n2) | ((unsigned)f32_to_bf16(n3) << 16);
        int chunk = lane >> 1;
        int pos = (chunk & 16) | ((chunk ^ sl) & 15);
        unsigned int* dst = (unsigned int*)((char*)mn + sl * 512 + pos * 16 + (lane & 1) * 8);
        dst[0] = p0; dst[1] = p1;
    }
    __syncthreads();

    bf16x8 af[8];
    #pragma unroll
    for (int ks = 0; ks < 8; ++ks)
        af[ks] = *(const bf16x8*)(Wbf + (wv * 8 + ks) * 512 + lane * 8);

    f32x4 acc[2];
    acc[0] = (f32x4){0.f, 0.f, 0.f, 0.f};
    acc[1] = (f32x4){0.f, 0.f, 0.f, 0.f};
    #pragma unroll
    for (int ks = 0; ks < 8; ++ks) {
        #pragma unroll
        for (int nb = 0; nb < 2; ++nb) {
            int sl = nb * 16 + l15;
            int chunk = ks * 4 + quad;
            int pos = (chunk & 16) | ((chunk ^ sl) & 15);
            bf16x8 bf = *(const bf16x8*)((char*)mn + sl * 512 + pos * 16);
            acc[nb] = __builtin_amdgcn_mfma_f32_16x16x32_bf16(af[ks], bf, acc[nb], 0, 0, 0);
        }
    }

    const float* bsrc = (wv < 2) ? b1 : b2;
    f32x4 bias = *(const f32x4*)(bsrc + (wv & 1) * 16 + quad * 4);
    unsigned short* sbase = stg + (wv >> 1) * 1024 + (wv & 1) * 512 + quad * 32;
    #pragma unroll
    for (int nb = 0; nb < 2; ++nb) {
        int sl = nb * 16 + l15;
        int soff = ((sl >> 3) & 3) * 128 + (sl & 7);
        #pragma unroll
        for (int reg = 0; reg < 4; ++reg)
            sbase[soff + reg * 8] = f32_to_bf16(acc[nb][reg] + bias[reg]);
    }
    __syncthreads();

    int part = tid >> 7, blk = (tid >> 6) & 1, l = tid & 63;
    unsigned short* gdst = (part ? B2f : A2f) + ((i * 2 + blk) * 4 + sblk) * 512 + l * 8;
    *(bf16x8*)gdst = *(const bf16x8*)(stg + tid * 8);
}

// ---------------- K2: fused GEMM1+GEMM2, 64-pair tiles, v2 ----------------
// 1024 blocks (XCD-chunked), 512 threads = 8 waves, 128 KB LDS, 1 blk/CU.
// o LDS layout: byte = chunk*1024 + (pair ^ swz6(chunk&63))*16 + (e&7)*2,
//   chunk = e>>3 in [0,128), e = c*32+d, pair = il*8+jl in [0,64).
// Stage A: 2 passes over j-halves, per-wave acc[4][4] (round-0 register shape).
// Stage B: waves = (zg 4) x (kh 2); each wave covers ALL 64 pairs over half
//   the K range -> wof read once per block (256 KB). LDS partial reduction.
__global__ __launch_bounds__(512, 2) void k_fused(
    const unsigned short* __restrict__ A2f, const unsigned short* __restrict__ B2f,
    const unsigned short* __restrict__ wof, const float* __restrict__ bo,
    float* __restrict__ out)
{
    __shared__ char olds[131072];
    int bid = blockIdx.x;
    int sb = (bid & 7) * 128 + (bid >> 3);   // bijective XCD chunking (1024%8==0)
    int bx = sb & 31, by = sb >> 5;          // bx: 8 i's, by: 8 j's
    int tid = threadIdx.x, wv = tid >> 6, lane = tid & 63;
    int quad = lane >> 4, l15 = lane & 15;
    int wm = wv & 1, wn = wv >> 1;           // wm: row half, wn: col group [0,4)

    // ---- Stage A: o[64 pairs][1024] = (8j x 32d) x (8i x 32c), K = 128 s ----
    const unsigned short* Abase = A2f + (size_t)((bx * 16 + wn * 4) * 4) * 512 + lane * 8;

    bf16x8 bn[4][4];                          // held A-side (cols) frags
    #pragma unroll
    for (int nb = 0; nb < 4; ++nb)
        #pragma unroll
        for (int ks = 0; ks < 4; ++ks)
            bn[ks][nb] = *(const bf16x8*)(Abase + (size_t)(nb * 4 + ks) * 512);

    #pragma unroll
    for (int pass = 0; pass < 2; ++pass) {
        const unsigned short* Bbase = B2f + (size_t)((by * 16 + pass * 8 + wm * 4) * 4) * 512 + lane * 8;
        f32x4 acc[4][4];
        #pragma unroll
        for (int a = 0; a < 4; ++a)
            #pragma unroll
            for (int b = 0; b < 4; ++b) acc[a][b] = (f32x4){0.f, 0.f, 0.f, 0.f};

        bf16x8 amC[4], amN[4];
        #pragma unroll
        for (int mb = 0; mb < 4; ++mb)
            amC[mb] = *(const bf16x8*)(Bbase + (size_t)(mb * 4) * 512);

        #pragma unroll
        for (int ks = 0; ks < 4; ++ks) {
            if (ks < 3) {
                #pragma unroll
                for (int mb = 0; mb < 4; ++mb)
                    amN[mb] = *(const bf16x8*)(Bbase + (size_t)(mb * 4 + ks + 1) * 512);
            }
            #pragma unroll
            for (int mb = 0; mb < 4; ++mb)
                #pragma unroll
                for (int nb = 0; nb < 4; ++nb)
                    acc[mb][nb] = __builtin_amdgcn_mfma_f32_16x16x32_bf16(amC[mb], bn[ks][nb], acc[mb][nb], 0, 0, 0);
            #pragma unroll
            for (int mb = 0; mb < 4; ++mb) amC[mb] = amN[mb];
        }

        // o-write: row m_=(jl,d) (B2f side), col n_=(il,c) (A2f side)
        #pragma unroll
        for (int mb = 0; mb < 4; ++mb) {
            int m_ = wm * 64 + mb * 16 + quad * 4;
            int d0 = m_ & 31;
            int jl = pass * 4 + (m_ >> 5);
            #pragma unroll
            for (int nb = 0; nb < 4; ++nb) {
                int n_ = wn * 64 + nb * 16 + l15;
                int c = n_ & 31, il = n_ >> 5;
                int pair = il * 8 + jl;
                int e0 = c * 32 + d0;
                int chunk = e0 >> 3;
                int phys = pair ^ swz6(chunk & 63);
                f32x4 a4 = acc[mb][nb];
                unsigned int p0 = (unsigned)f32_to_bf16(a4[0]) | ((unsigned)f32_to_bf16(a4[1]) << 16);
                unsigned int p1 = (unsigned)f32_to_bf16(a4[2]) | ((unsigned)f32_to_bf16(a4[3]) << 16);
                u32x2 pv = {p0, p1};
                *(u32x2*)(olds + chunk * 1024 + phys * 16 + (e0 & 7) * 2) = pv;
            }
        }
    }

    // ---- Stage B: wave (zg,kh) computes partial D[32 zo][64 pair] over 16 kt ----
    int zg = wv >> 1, kh = wv & 1, kt0 = kh * 16;
    const unsigned short* wbase = wof + (size_t)(zg * 64) * 512 + lane * 8;

    bf16x8 af2[4][2], bfr[4][4];
    // wof prologue loads BEFORE the barrier (no LDS dependency).
    #pragma unroll
    for (int p = 0; p < 3; ++p)
        #pragma unroll
        for (int zb = 0; zb < 2; ++zb)
            af2[p][zb] = *(const bf16x8*)(wbase + (size_t)(zb * 32 + kt0 + p) * 512);

    __syncthreads();

    #pragma unroll
    for (int p = 0; p < 3; ++p)
        #pragma unroll
        for (int pb = 0; pb < 4; ++pb) {
            int pair = pb * 16 + l15;
            int chunk = (kt0 + p) * 4 + quad;
            int phys = pair ^ swz6(chunk & 63);
            bfr[p][pb] = *(const bf16x8*)(olds + chunk * 1024 + phys * 16);
        }

    f32x4 acc2[2][4];
    #pragma unroll
    for (int a = 0; a < 2; ++a)
        #pragma unroll
        for (int b = 0; b < 4; ++b) acc2[a][b] = (f32x4){0.f, 0.f, 0.f, 0.f};

    #pragma unroll
    for (int kt = 0; kt < 16; ++kt) {
        int slot = kt & 3;
        if (kt < 13) {
            int pf = kt0 + kt + 3, ps = (kt + 3) & 3;
            #pragma unroll
            for (int zb = 0; zb < 2; ++zb)
                af2[ps][zb] = *(const bf16x8*)(wbase + (size_t)(zb * 32 + pf) * 512);
            #pragma unroll
            for (int pb = 0; pb < 4; ++pb) {
                int pair = pb * 16 + l15;
                int chunk = pf * 4 + quad;
                int phys = pair ^ swz6(chunk & 63);
                bfr[ps][pb] = *(const bf16x8*)(olds + chunk * 1024 + phys * 16);
            }
        }
        #pragma unroll
        for (int zb = 0; zb < 2; ++zb)
            #pragma unroll
            for (int pb = 0; pb < 4; ++pb)
                acc2[zb][pb] = __builtin_amdgcn_mfma_f32_16x16x32_bf16(af2[slot][zb], bfr[slot][pb], acc2[zb][pb], 0, 0, 0);
    }

    // ---- K-split reduction through LDS (reuse olds; conflict-free f32x4 slots) ----
    __syncthreads();                          // all olds reads done
    f32x4* red = (f32x4*)olds;
    if (kh == 1) {
        #pragma unroll
        for (int zb = 0; zb < 2; ++zb)
            #pragma unroll
            for (int pb = 0; pb < 4; ++pb)
                red[(((zg * 2 + zb) * 4 + pb) << 6) + quad * 16 + l15] = acc2[zb][pb];
    }
    __syncthreads();
    if (kh == 0) {
        #pragma unroll
        for (int zb = 0; zb < 2; ++zb) {
            int zo = zg * 32 + zb * 16 + quad * 4;
            f32x4 b4 = *(const f32x4*)(bo + zo);
            #pragma unroll
            for (int pb = 0; pb < 4; ++pb) {
                f32x4 part = red[(((zg * 2 + zb) * 4 + pb) << 6) + quad * 16 + l15];
                int pair = pb * 16 + l15;
                int i = bx * 8 + (pair >> 3);
                int j = by * 8 + (pair & 7);
                f32x4 v;
                #pragma unroll
                for (int reg = 0; reg < 4; ++reg)
                    v[reg] = (acc2[zb][pb][reg] + part[reg] + b4[reg]) * (1.0f / 128.0f);
                *(f32x4*)(out + ((size_t)(i * 256 + j)) * 128 + zo) = v;
            }
        }
    }
}

extern "C" void kernel_launch(void* const* d_in, const int* in_sizes, int n_in,
                              void* d_out, int out_size, void* d_ws, size_t ws_size,
                              hipStream_t stream) {
    const float* m   = (const float*)d_in[0];
    const float* lnw = (const float*)d_in[1];
    const float* lnb = (const float*)d_in[2];
    const float* w1  = (const float*)d_in[3];
    const float* b1  = (const float*)d_in[4];
    const float* w2  = (const float*)d_in[5];
    const float* b2  = (const float*)d_in[6];
    const float* wo  = (const float*)d_in[7];
    const float* bo  = (const float*)d_in[8];
    float* out = (float*)d_out;
    char* ws = (char*)d_ws;

    unsigned short* Wbf = (unsigned short*)(ws);                            // 32 KB
    unsigned short* wof = (unsigned short*)(ws + 32768);                    // 256 KB
    unsigned short* A2f = (unsigned short*)(ws + 32768 + 262144);           // 2 MB
    unsigned short* B2f = (unsigned short*)(ws + 32768 + 262144 + 2097152); // 2 MB

    hipLaunchKernelGGL(k_prep, dim3(512), dim3(256), 0, stream, w1, w2, wo, Wbf, wof);
    hipLaunchKernelGGL(k_ln_proj, dim3(1024), dim3(256), 0, stream,
                       m, lnw, lnb, b1, b2, Wbf, A2f, B2f);
    hipLaunchKernelGGL(k_fused, dim3(1024), dim3(512), 0, stream,
                       A2f, B2f, wof, bo, out);
}